// Round 10
// baseline (425.355 us; speedup 1.0000x reference)
//
#include <hip/hip_runtime.h>
#include <hip/hip_bf16.h>

// ---------------------------------------------------------------------------
// KascadeReuseAttention: B=2,S=4096,H=16,D=128, TILE=128, T=32, TOPK=7(+local)
// R10: GEMM -> tile 128x256, 256 thr (4 waves, 2Mx2N, per-wave 64x128 same as
// R9), 3-slot LDS ring (72KB -> 2 independent blocks/CU for barrier cover),
// counted vmcnt(6) (never 0 in loop). Fused QKV+RoPE+V^T epilogue unchanged.
// wtrans x4 merged into one launch. Attn unchanged.
// ---------------------------------------------------------------------------

typedef __bf16 bf16_t;
using bf16x8 = __attribute__((ext_vector_type(8))) __bf16;
using bf16x4 = __attribute__((ext_vector_type(4))) __bf16;
using f32x4  = __attribute__((ext_vector_type(4))) float;

typedef const __attribute__((address_space(1))) void* gas_ptr;
typedef __attribute__((address_space(3))) void* las_ptr;

__device__ __forceinline__ void async_copy16(const void* g, void* l) {
  __builtin_amdgcn_global_load_lds((gas_ptr)g, (las_ptr)l, 16, 0, 0);
}

__device__ __forceinline__ f32x4 mfma16x16x32(bf16x8 a, bf16x8 b, f32x4 c) {
  return __builtin_amdgcn_mfma_f32_16x16x32_bf16(a, b, c, 0, 0, 0);
}

// ---------------- elementwise f32 -> bf16 (vectorized) ----------------------
__global__ void cvt_f32_bf16(const float* __restrict__ X, bf16_t* __restrict__ Y) {
  int idx = blockIdx.x * 256 + threadIdx.x;
  float4 v = ((const float4*)X)[idx];
  bf16x4 r;
  r.x = (bf16_t)v.x; r.y = (bf16_t)v.y; r.z = (bf16_t)v.z; r.w = (bf16_t)v.w;
  ((bf16x4*)Y)[idx] = r;
}

// -------- weight transpose+convert x4 in one launch: W f32 -> Wt bf16 -------
__global__ void wtrans4(const float* __restrict__ wq, const float* __restrict__ wk,
                        const float* __restrict__ wv, const float* __restrict__ wo,
                        bf16_t* __restrict__ wcat, bf16_t* __restrict__ wot) {
  __shared__ bf16_t t[64][66];
  const int z = blockIdx.z;
  const float* W = (z == 0) ? wq : (z == 1) ? wk : (z == 2) ? wv : wo;
  bf16_t* Wt = (z == 3) ? wot : (wcat + (size_t)z * 2048 * 2048);
  const int r0 = blockIdx.x * 64, c0 = blockIdx.y * 64;
  const int tx = threadIdx.x & 63, ty = threadIdx.x >> 6;
  #pragma unroll
  for (int i = 0; i < 16; ++i) {
    int r = ty + 4 * i;
    t[r][tx] = (bf16_t)W[(size_t)(r0 + r) * 2048 + c0 + tx];
  }
  __syncthreads();
  #pragma unroll
  for (int i = 0; i < 16; ++i) {
    int n = ty + 4 * i;
    Wt[(size_t)(c0 + n) * 2048 + r0 + tx] = t[tx][n];
  }
}

// ---------------- GEMM 128x256 pipelined: C[8192][Ntot] = A * Bt^T ----------
// 4 waves as 2M x 2N (per-wave 64Mx128N; full head span in-thread for rope).
// LDS: 3-slot ring of A[128][32]+B[256][32] bf16 panels (24KB/slot, 72KB
// total -> 2 independent blocks/CU: desynced barriers cover each other).
// Swizzle: rows of 4x16B chunks, chunk ^= (row>>1)&3 (write-source + read).
// Phase t (64 total): {STAGE(t+2): 6 gload_lds | 12 ds_read frags |
// setprio(1) 32 MFMA setprio(0) | vmcnt(6) | raw s_barrier}.
// Ledger: outstanding <= 6(t+1)+6(t+2)=12; vmcnt(6) at phase-t end retires
// tile t+1 -> phase t+1 reads safe after barrier. STAGE(t+2) overwrites slot
// (t+2)%3, last read at phase t-1: 1 barrier + 32-MFMA cluster + mem latency
// upstream of the write landing -> WAR safe. vmcnt(0) only at t>=62.
// mode 0: f32 C row-major [8192][2048] (nb=8).
// mode 1: fused QKV (nb=24): proj=col>>11 -> Q,K rope'd bf16 [B,H,S,D];
//         V -> V^T bf16 [B,H,D,S].
__global__ __launch_bounds__(256, 2) void gemm128(
    const bf16_t* __restrict__ A, const bf16_t* __restrict__ Bt,
    int nb, int mode, float* __restrict__ Cf,
    bf16_t* __restrict__ outQ, bf16_t* __restrict__ outK,
    bf16_t* __restrict__ outVT,
    const float* __restrict__ cosT, const float* __restrict__ sinT)
{
  __shared__ bf16_t Apan[3][4096];    // [128 rows][32 k] = 8KB per slot
  __shared__ bf16_t Bpan[3][8192];    // [256 rows][32 k] = 16KB per slot
  const int bid = blockIdx.x;
  const int cpx = gridDim.x >> 3;
  const int swz = (bid & 7) * cpx + (bid >> 3);   // XCD-chunked (grid%8==0)
  const int bm = (swz / nb) * 128, bn = (swz % nb) * 256;
  const int tid = threadIdx.x;
  const int w = tid >> 6, l = tid & 63;
  const int wr = w >> 1, wc = w & 1;              // 2M x 2N
  const int fr = l & 15, g4 = l >> 4;

  // staging: A 2 chunks/thread, B 4 chunks/thread over [rows][4 ch] panels
  const bf16_t* aS[2];
  const bf16_t* bS[4];
  int dA[2], dB[4];
  #pragma unroll
  for (int i = 0; i < 2; ++i) {
    int c = tid + i * 256;              // 0..511
    int row = c >> 2, ch = c & 3;
    aS[i] = A + (size_t)(bm + row) * 2048 + (ch ^ ((row >> 1) & 3)) * 8;
    dA[i] = c * 16;
  }
  #pragma unroll
  for (int i = 0; i < 4; ++i) {
    int c = tid + i * 256;              // 0..1023
    int row = c >> 2, ch = c & 3;
    bS[i] = Bt + (size_t)(bn + row) * 2048 + (ch ^ ((row >> 1) & 3)) * 8;
    dB[i] = c * 16;
  }

  // frag-read byte offsets within panels (row stride 64B)
  int aOff[4], bOff[8];
  #pragma unroll
  for (int m = 0; m < 4; ++m) {
    int R = wr * 64 + m * 16 + fr;
    aOff[m] = R * 64 + ((g4 ^ ((R >> 1) & 3)) << 4);
  }
  #pragma unroll
  for (int n = 0; n < 8; ++n) {
    int R = wc * 128 + n * 16 + fr;
    bOff[n] = R * 64 + ((g4 ^ ((R >> 1) & 3)) << 4);
  }

  f32x4 acc[4][8];
  #pragma unroll
  for (int m = 0; m < 4; ++m)
    #pragma unroll
    for (int n = 0; n < 8; ++n) acc[m][n] = (f32x4){0.f, 0.f, 0.f, 0.f};

  auto STAGE = [&](int t) {            // stage K-tile t into slot t%3
    const int slot = t % 3;
    const int kb = t * 32;
    char* pA = (char*)&Apan[slot][0];
    char* pB = (char*)&Bpan[slot][0];
    #pragma unroll
    for (int i = 0; i < 2; ++i) async_copy16(aS[i] + kb, pA + dA[i]);
    #pragma unroll
    for (int i = 0; i < 4; ++i) async_copy16(bS[i] + kb, pB + dB[i]);
  };

  STAGE(0);
  STAGE(1);
  asm volatile("s_waitcnt vmcnt(6)" ::: "memory");   // tile 0 landed
  __builtin_amdgcn_sched_barrier(0);
  __builtin_amdgcn_s_barrier();
  __builtin_amdgcn_sched_barrier(0);

  #pragma unroll 1
  for (int phi = 0; phi < 64; ++phi) {
    const int slot = phi % 3;
    const char* pa = (const char*)&Apan[slot][0];
    const char* pb = (const char*)&Bpan[slot][0];
    if (phi < 62) STAGE(phi + 2);
    bf16x8 af[4], bfr[8];
    #pragma unroll
    for (int m = 0; m < 4; ++m) af[m] = *(const bf16x8*)(pa + aOff[m]);
    #pragma unroll
    for (int n = 0; n < 8; ++n) bfr[n] = *(const bf16x8*)(pb + bOff[n]);
    __builtin_amdgcn_s_setprio(1);
    #pragma unroll
    for (int m = 0; m < 4; ++m)
      #pragma unroll
      for (int n = 0; n < 8; ++n)
        acc[m][n] = mfma16x16x32(af[m], bfr[n], acc[m][n]);
    __builtin_amdgcn_s_setprio(0);
    if (phi < 62) asm volatile("s_waitcnt vmcnt(6)" ::: "memory");
    else          asm volatile("s_waitcnt vmcnt(0)" ::: "memory");
    __builtin_amdgcn_sched_barrier(0);
    __builtin_amdgcn_s_barrier();      // raw: no implicit full drain
    __builtin_amdgcn_sched_barrier(0);
  }

  if (mode == 0) {
    #pragma unroll
    for (int m = 0; m < 4; ++m)
      #pragma unroll
      for (int n = 0; n < 8; ++n)
        #pragma unroll
        for (int j = 0; j < 4; ++j) {
          int row = bm + wr * 64 + m * 16 + g4 * 4 + j;
          int col = bn + wc * 128 + n * 16 + fr;
          Cf[(size_t)row * 2048 + col] = acc[m][n][j];
        }
    return;
  }

  // ---- fused QKV epilogue ----
  const int colbase = bn + wc * 128;          // wave-uniform, multiple of 128
  const int proj = colbase >> 11;             // 0=Q 1=K 2=V
  const int hh = (colbase & 2047) >> 7;
  if (proj == 2) {
    // V^T [BH*128 d][4096 s]: j-quad packs to one bf16x4 store
    #pragma unroll
    for (int m = 0; m < 4; ++m) {
      int row0 = bm + wr * 64 + m * 16 + g4 * 4;
      int b_ = row0 >> 12, sr = row0 & 4095;
      #pragma unroll
      for (int n = 0; n < 8; ++n) {
        int d_ = n * 16 + fr;
        bf16x4 pkv;
        #pragma unroll
        for (int j = 0; j < 4; ++j) pkv[j] = (bf16_t)acc[m][n][j];
        *(bf16x4*)&outVT[(((size_t)(b_ * 16 + hh)) * 128 + d_) * 4096 + sr] = pkv;
      }
    }
  } else {
    bf16_t* dst_ = proj ? outK : outQ;
    #pragma unroll
    for (int m = 0; m < 4; ++m) {
      int row0 = bm + wr * 64 + m * 16 + g4 * 4;
      int b_ = row0 >> 12, s0 = row0 & 4095;
      size_t hbase = ((size_t)(b_ * 16 + hh)) * 4096;
      #pragma unroll
      for (int n = 0; n < 4; ++n) {
        int d = n * 16 + fr;
        #pragma unroll
        for (int j = 0; j < 4; ++j) {
          int s = s0 + j;
          float c  = cosT[s * 64 + d];
          float sn = sinT[s * 64 + d];
          float x0 = acc[m][n][j], x1 = acc[m][n + 4][j];
          dst_[(hbase + s) * 128 + d]      = (bf16_t)(x0 * c - x1 * sn);
          dst_[(hbase + s) * 128 + d + 64] = (bf16_t)(x1 * c + x0 * sn);
        }
      }
    }
  }
}

// ---------------- sparse flash attention (8 waves x 16 q-rows) --------------
// block = (b,h,qt): 512 threads, wave owns 16 q-rows -> 4 waves/SIMD at
// 2 blocks/CU (LDS exactly 80KB). Active tiles only (tsel<=qt), packed 5-bit
// reg list. KVBLK=64 double-buffered via gload_lds (source-preswizzled
// chunk^=row&7); stage s+1 before compute s; 1 barrier/step. Mask only local
// tile; defer-max (T13). Swapped QK^T / PV; P packed bf16x4 per-wave LDS.
__global__ __launch_bounds__(512, 4) void attn_kernel(
    const bf16_t* __restrict__ Qf, const bf16_t* __restrict__ Kf,
    const bf16_t* __restrict__ Vt, const int* __restrict__ anchors,
    bf16_t* __restrict__ outB)   // [B,S,2048] bf16
{
  __shared__ bf16_t Kl[2][8192];    // [64 tok][128 d] swizzled, 16KB each
  __shared__ bf16_t Vl[2][8192];    // [128 d][64 tok] swizzled, 16KB each
  __shared__ bf16_t Pbuf[8][1024];  // per-wave 2KB  (total LDS = 80KB exact)
  const int orig = blockIdx.x;
  const int blk = (orig & 7) * 128 + (orig >> 3);   // XCD-chunked swizzle
  const int qt = 31 - (blk & 31);                   // high-qt (long) blocks first
  const int h = (blk >> 5) & 15, b = blk >> 9;
  const int bh = b * 16 + h;
  const int tid = threadIdx.x, w = tid >> 6, l = tid & 63;
  const int fr = l & 15, g4 = l >> 4;
  const float scale = 0.08838834764831845f;   // 1/sqrt(128)

  // ---- packed active-tile list (identical in every thread) ----
  const int* anc = anchors + ((size_t)bh * 32 + qt) * 7;
  unsigned long long pk = 0;
  int nt = 0;
  #pragma unroll
  for (int t = 0; t < 7; ++t) {
    int v = anc[t];
    if (v <= qt) { pk |= (unsigned long long)v << (5 * nt); ++nt; }
  }
  pk |= (unsigned long long)qt << (5 * nt); ++nt;   // local tile last
  const int NS = nt * 2;

  const bf16_t* Qbase = Qf + (size_t)bh * 4096 * 128;
  const bf16_t* Kbase = Kf + (size_t)bh * 4096 * 128;
  const bf16_t* Vbase = Vt + (size_t)bh * 128 * 4096;
  char* P = (char*)&Pbuf[w][0];

  auto STAGE = [&](int tb2, int p) {
    const bf16_t* ksrc = Kbase + (size_t)tb2 * 128;
    const bf16_t* vsrc = Vbase + tb2;
    char* kd = (char*)&Kl[p][0];
    char* vd = (char*)&Vl[p][0];
    #pragma unroll
    for (int i = 0; i < 2; ++i) {
      int c = tid + i * 512;                 // 0..1023
      int kr = c >> 4, kcol = c & 15;        // K: 64 rows x 16 chunks
      async_copy16(ksrc + (size_t)kr * 128 + (size_t)((kcol ^ (kr & 7)) * 8),
                   kd + c * 16);
      int vr = c >> 3, vcol = c & 7;         // V^T: 128 rows x 8 chunks
      async_copy16(vsrc + (size_t)vr * 4096 + (size_t)((vcol ^ (vr & 7)) * 8),
                   vd + c * 16);
    }
  };

  // Q fragments (B-operand: col = q-row, k-chunk g4*8), direct from global
  const int qrow = qt * 128 + w * 16 + fr;
  bf16x8 aq[4];
  #pragma unroll
  for (int kc = 0; kc < 4; ++kc)
    aq[kc] = *(const bf16x8*)(Qbase + (size_t)qrow * 128 + kc * 32 + g4 * 8);

  STAGE((int)(pk & 31) * 128, 0);
  __syncthreads();   // step-0 buffers landed

  float mrun = -1e30f, lrun = 0.f;
  f32x4 o[8];
  #pragma unroll
  for (int nd = 0; nd < 8; ++nd) o[nd] = (f32x4){0.f, 0.f, 0.f, 0.f};

  for (int s = 0; s < NS; ++s) {
    const int p = s & 1;
    const int ts = (int)((pk >> (5 * (s >> 1))) & 31);
    const bool domask = (ts == qt);
    if (s + 1 < NS) {
      int s1 = s + 1;
      int ts1 = (int)((pk >> (5 * (s1 >> 1))) & 31);
      STAGE(ts1 * 128 + (s1 & 1) * 64, p ^ 1);
    }

    // ---- S^T = K Q^T from Kl[p]: sc[n], rows=tok(g4*4+j), cols=q(fr) ----
    f32x4 sc[4];
    #pragma unroll
    for (int n = 0; n < 4; ++n) sc[n] = (f32x4){0.f, 0.f, 0.f, 0.f};
    #pragma unroll
    for (int kc = 0; kc < 4; ++kc) {
      bf16x8 kf[4];
      #pragma unroll
      for (int n = 0; n < 4; ++n) {
        int r = n * 16 + fr;
        kf[n] = *(const bf16x8*)((const char*)&Kl[p][0] +
                 r * 256 + (((kc * 4 + g4) ^ (r & 7)) << 4));
      }
      #pragma unroll
      for (int n = 0; n < 4; ++n)
        sc[n] = mfma16x16x32(kf[n], aq[kc], sc[n]);
    }

    // ---- mask (local tile only) + online softmax ----
    float rmax = -1e30f;
    if (domask) {
      const int qr = w * 16 + fr;            // row within tile
      #pragma unroll
      for (int n = 0; n < 4; ++n)
        #pragma unroll
        for (int j = 0; j < 4; ++j) {
          float lg = sc[n][j] * scale;
          int tok = (s & 1) * 64 + n * 16 + g4 * 4 + j;
          if (tok > qr) lg = -1e10f;
          sc[n][j] = lg;
          rmax = fmaxf(rmax, lg);
        }
    } else {
      #pragma unroll
      for (int n = 0; n < 4; ++n)
        #pragma unroll
        for (int j = 0; j < 4; ++j) {
          float lg = sc[n][j] * scale;
          sc[n][j] = lg;
          rmax = fmaxf(rmax, lg);
        }
    }
    rmax = fmaxf(rmax, __shfl_xor(rmax, 16));
    rmax = fmaxf(rmax, __shfl_xor(rmax, 32));
    if (__any(rmax > mrun + 8.f)) {          // defer-max (T13)
      float mnew = fmaxf(mrun, rmax);
      float alpha = __expf(mrun - mnew);
      lrun *= alpha;
      #pragma unroll
      for (int nd = 0; nd < 8; ++nd)
        #pragma unroll
        for (int j = 0; j < 4; ++j) o[nd][j] *= alpha;
      mrun = mnew;
    }
    float rsum = 0.f;
    #pragma unroll
    for (int n = 0; n < 4; ++n) {
      bf16x4 pkv;
      #pragma unroll
      for (int j = 0; j < 4; ++j) {
        float pe = __expf(sc[n][j] - mrun);
        rsum += pe;
        pkv[j] = (bf16_t)pe;
      }
      int off = fr * 128 + ((((n << 1) | (g4 >> 1)) ^ (fr & 7)) << 4) + ((g4 & 1) << 3);
      *(bf16x4*)(P + off) = pkv;
    }
    rsum += __shfl_xor(rsum, 16);
    rsum += __shfl_xor(rsum, 32);
    lrun += rsum;

    // ---- O^T += V^T P from Vl[p] + per-wave P ----
    #pragma unroll
    for (int kc2 = 0; kc2 < 2; ++kc2) {
      bf16x8 av[8];
      #pragma unroll
      for (int nd = 0; nd < 8; ++nd) {
        int r = nd * 16 + fr;
        av[nd] = *(const bf16x8*)((const char*)&Vl[p][0] +
                  r * 128 + (((kc2 * 4 + g4) ^ (r & 7)) << 4));
      }
      bf16x8 bp = *(const bf16x8*)(P + fr * 128 + ((((kc2 << 2) | g4) ^ (fr & 7)) << 4));
      #pragma unroll
      for (int nd = 0; nd < 8; ++nd)
        o[nd] = mfma16x16x32(av[nd], bp, o[nd]);
    }
    __syncthreads();   // next staging landed + all waves done with buf p
  }

  // ---- epilogue: normalize; O^T -> per-wave scratch (Kl dead) -> store ----
  {
    char* E = (char*)&Kl[0][0] + w * 4096;   // 16 rows x 256B per wave
    float inv = 1.0f / lrun;
    #pragma unroll
    for (int nd = 0; nd < 8; ++nd) {
      bf16x4 pkv;
      #pragma unroll
      for (int j = 0; j < 4; ++j) pkv[j] = (bf16_t)(o[nd][j] * inv);
      int off = fr * 256 + ((((nd << 1) | (g4 >> 1)) ^ (fr & 7)) << 4) + ((g4 & 1) << 3);
      *(bf16x4*)(E + off) = pkv;
    }
    #pragma unroll
    for (int i = 0; i < 4; ++i) {
      int r = i * 4 + g4;
      int off = r * 256 + ((fr ^ (r & 7)) << 4);
      bf16x8 vrow = *(const bf16x8*)(E + off);
      size_t gaddr = (((size_t)b * 4096 + qt * 128 + w * 16 + r) * 2048)
                     + h * 128 + fr * 8;
      *(bf16x8*)(outB + gaddr) = vrow;
    }
  }
}

// ---------------------------------------------------------------------------
// workspace layout (bytes)
#define OFF_XB   ((size_t)0)            // x bf16            [8192][2048]  32MB
#define OFF_WCAT ((size_t)33554432)     // concat wq^T|wk^T|wv^T bf16 [6144][2048] 24MB
#define OFF_WOT  ((size_t)58720256)     // wo^T bf16 [2048][2048] 8MB
#define OFF_QF   ((size_t)67108864)     // Q bf16 [B,H,S,D]  32MB
#define OFF_KF   ((size_t)100663296)    // K bf16 [B,H,S,D]  32MB
#define OFF_AT   ((size_t)134217728)    // attn out [B,S,2048] bf16 32MB
#define OFF_VT   ((size_t)167772160)    // V^T bf16 [B,H,D,S] 32MB

extern "C" void kernel_launch(void* const* d_in, const int* in_sizes, int n_in,
                              void* d_out, int out_size, void* d_ws, size_t ws_size,
                              hipStream_t stream) {
  (void)in_sizes; (void)n_in; (void)out_size; (void)ws_size;
  const float* x    = (const float*)d_in[0];
  const float* wq   = (const float*)d_in[1];
  const float* wk   = (const float*)d_in[2];
  const float* wv   = (const float*)d_in[3];
  const float* wo   = (const float*)d_in[4];
  const float* cosT = (const float*)d_in[5];
  const float* sinT = (const float*)d_in[6];
  const int*   anc  = (const int*)d_in[7];
  float* out = (float*)d_out;
  char* ws = (char*)d_ws;

  bf16_t* xb   = (bf16_t*)(ws + OFF_XB);
  bf16_t* wcat = (bf16_t*)(ws + OFF_WCAT);
  bf16_t* wot  = (bf16_t*)(ws + OFF_WOT);
  bf16_t* Qf   = (bf16_t*)(ws + OFF_QF);
  bf16_t* Kf   = (bf16_t*)(ws + OFF_KF);
  bf16_t* Vt   = (bf16_t*)(ws + OFF_VT);
  bf16_t* attnB = (bf16_t*)(ws + OFF_AT);

  cvt_f32_bf16<<<16384, 256, 0, stream>>>(x, xb);
  wtrans4<<<dim3(32, 32, 4), 256, 0, stream>>>(wq, wk, wv, wo, wcat, wot);
  // fused QKV projection + RoPE + V^T (grid 1536 = 64 M-blocks x 24 N-blocks)
  gemm128<<<1536, 256, 0, stream>>>(xb, wcat, 24, 1, nullptr, Qf, Kf, Vt, cosT, sinT);
  attn_kernel<<<1024, 512, 0, stream>>>(Qf, Kf, Vt, anc, attnB);
  // output projection (grid 512 = 64 x 8)
  gemm128<<<512, 256, 0, stream>>>(attnB, wot, 8, 0, out, nullptr, nullptr, nullptr,
                                   nullptr, nullptr);
}

// Round 11
// 375.607 us; speedup vs baseline: 1.1324x; 1.1324x over previous
//
#include <hip/hip_runtime.h>
#include <hip/hip_bf16.h>

// ---------------------------------------------------------------------------
// KascadeReuseAttention: B=2,S=4096,H=16,D=128, TILE=128, T=32, TOPK=7(+local)
// R11: GEMM reverted to R9 (best measured: BK=64, 2-slot, 1 barrier/phase).
// attn: KVBLK=32 -> LDS 40KB -> 4 blocks/CU (cross-block barrier cover).
// wtrans4 merged launch kept.
// ---------------------------------------------------------------------------

typedef __bf16 bf16_t;
using bf16x8 = __attribute__((ext_vector_type(8))) __bf16;
using bf16x4 = __attribute__((ext_vector_type(4))) __bf16;
using f32x4  = __attribute__((ext_vector_type(4))) float;

typedef const __attribute__((address_space(1))) void* gas_ptr;
typedef __attribute__((address_space(3))) void* las_ptr;

__device__ __forceinline__ void async_copy16(const void* g, void* l) {
  __builtin_amdgcn_global_load_lds((gas_ptr)g, (las_ptr)l, 16, 0, 0);
}

__device__ __forceinline__ f32x4 mfma16x16x32(bf16x8 a, bf16x8 b, f32x4 c) {
  return __builtin_amdgcn_mfma_f32_16x16x32_bf16(a, b, c, 0, 0, 0);
}

// ---------------- elementwise f32 -> bf16 (vectorized) ----------------------
__global__ void cvt_f32_bf16(const float* __restrict__ X, bf16_t* __restrict__ Y) {
  int idx = blockIdx.x * 256 + threadIdx.x;
  float4 v = ((const float4*)X)[idx];
  bf16x4 r;
  r.x = (bf16_t)v.x; r.y = (bf16_t)v.y; r.z = (bf16_t)v.z; r.w = (bf16_t)v.w;
  ((bf16x4*)Y)[idx] = r;
}

// -------- weight transpose+convert x4 in one launch: W f32 -> Wt bf16 -------
__global__ void wtrans4(const float* __restrict__ wq, const float* __restrict__ wk,
                        const float* __restrict__ wv, const float* __restrict__ wo,
                        bf16_t* __restrict__ wcat, bf16_t* __restrict__ wot) {
  __shared__ bf16_t t[64][66];
  const int z = blockIdx.z;
  const float* W = (z == 0) ? wq : (z == 1) ? wk : (z == 2) ? wv : wo;
  bf16_t* Wt = (z == 3) ? wot : (wcat + (size_t)z * 2048 * 2048);
  const int r0 = blockIdx.x * 64, c0 = blockIdx.y * 64;
  const int tx = threadIdx.x & 63, ty = threadIdx.x >> 6;
  #pragma unroll
  for (int i = 0; i < 16; ++i) {
    int r = ty + 4 * i;
    t[r][tx] = (bf16_t)W[(size_t)(r0 + r) * 2048 + c0 + tx];
  }
  __syncthreads();
  #pragma unroll
  for (int i = 0; i < 16; ++i) {
    int n = ty + 4 * i;
    Wt[(size_t)(c0 + n) * 2048 + r0 + tx] = t[tx][n];
  }
}

// ---------------- GEMM 256x256 pipelined (R9, best measured) ----------------
// 8 waves as 4M x 2N (per-wave 64Mx128N; full head span in-thread for rope).
// LDS: 2-slot double buffer of A[256][64]+B[256][64] bf16 panels (128KiB).
// Swizzle: rows are 8 x 16B chunks; LDS[row][ch] = global[row][ch^(row&7)].
// Phase phi (32, BK=64): {kc0 frags | STAGE(phi+1) | kc0 MFMA x32 | kc1 frags
// | kc1 MFMA x32 | vmcnt(0) | raw s_barrier}.
// mode 0: f32 C row-major [8192][2048] (nb=8).
// mode 1: fused QKV (nb=24): Q,K rope'd bf16 [B,H,S,D]; V -> V^T [B,H,D,S].
__global__ __launch_bounds__(512, 2) void gemm256(
    const bf16_t* __restrict__ A, const bf16_t* __restrict__ Bt,
    int nb, int mode, float* __restrict__ Cf,
    bf16_t* __restrict__ outQ, bf16_t* __restrict__ outK,
    bf16_t* __restrict__ outVT,
    const float* __restrict__ cosT, const float* __restrict__ sinT)
{
  __shared__ bf16_t Apan[2][16384];   // [256 rows][64 k] bf16 = 32KB per slot
  __shared__ bf16_t Bpan[2][16384];
  const int bid = blockIdx.x;
  const int cpx = gridDim.x >> 3;
  const int swz = (bid & 7) * cpx + (bid >> 3);   // XCD-chunked (grid%8==0)
  const int bm = (swz / nb) * 256, bn = (swz % nb) * 256;
  const int tid = threadIdx.x;
  const int w = tid >> 6, l = tid & 63;
  const int wr = w >> 1, wc = w & 1;              // 4M x 2N
  const int fr = l & 15, g4 = l >> 4;

  const bf16_t* aS[4];
  const bf16_t* bS[4];
  int dst[4];
  #pragma unroll
  for (int i = 0; i < 4; ++i) {
    int c = tid + i * 512;
    int row = c >> 3, ch = c & 7;
    int sc = (ch ^ (row & 7)) * 8;
    aS[i] = A  + (size_t)(bm + row) * 2048 + sc;
    bS[i] = Bt + (size_t)(bn + row) * 2048 + sc;
    dst[i] = c * 16;
  }

  int aOff[2][4], bOff[2][8];
  #pragma unroll
  for (int kc = 0; kc < 2; ++kc) {
    #pragma unroll
    for (int m = 0; m < 4; ++m) {
      int R = wr * 64 + m * 16 + fr;
      aOff[kc][m] = R * 128 + (((kc * 4 + g4) ^ (R & 7)) << 4);
    }
    #pragma unroll
    for (int n = 0; n < 8; ++n) {
      int R = wc * 128 + n * 16 + fr;
      bOff[kc][n] = R * 128 + (((kc * 4 + g4) ^ (R & 7)) << 4);
    }
  }

  f32x4 acc[4][8];
  #pragma unroll
  for (int m = 0; m < 4; ++m)
    #pragma unroll
    for (int n = 0; n < 8; ++n) acc[m][n] = (f32x4){0.f, 0.f, 0.f, 0.f};

  auto STAGE = [&](int t) {        // stage K-tile t (64 wide) into slot t&1
    const int slot = t & 1;
    const int kb = t * 64;
    char* dA = (char*)&Apan[slot][0];
    char* dB = (char*)&Bpan[slot][0];
    #pragma unroll
    for (int i = 0; i < 4; ++i) {
      async_copy16(aS[i] + kb, dA + dst[i]);
      async_copy16(bS[i] + kb, dB + dst[i]);
    }
  };

  STAGE(0);
  __syncthreads();   // prologue: tile 0 landed (full drain, once)

  #pragma unroll 1
  for (int phi = 0; phi < 32; ++phi) {
    const int slot = phi & 1;
    const char* pa = (const char*)&Apan[slot][0];
    const char* pb = (const char*)&Bpan[slot][0];

    bf16x8 af0[4], bf0[8];
    #pragma unroll
    for (int m = 0; m < 4; ++m) af0[m] = *(const bf16x8*)(pa + aOff[0][m]);
    #pragma unroll
    for (int n = 0; n < 8; ++n) bf0[n] = *(const bf16x8*)(pb + bOff[0][n]);
    if (phi < 31) STAGE(phi + 1);
    __builtin_amdgcn_s_setprio(1);
    #pragma unroll
    for (int m = 0; m < 4; ++m)
      #pragma unroll
      for (int n = 0; n < 8; ++n)
        acc[m][n] = mfma16x16x32(af0[m], bf0[n], acc[m][n]);
    __builtin_amdgcn_s_setprio(0);

    bf16x8 af1[4], bf1[8];
    #pragma unroll
    for (int m = 0; m < 4; ++m) af1[m] = *(const bf16x8*)(pa + aOff[1][m]);
    #pragma unroll
    for (int n = 0; n < 8; ++n) bf1[n] = *(const bf16x8*)(pb + bOff[1][n]);
    __builtin_amdgcn_s_setprio(1);
    #pragma unroll
    for (int m = 0; m < 4; ++m)
      #pragma unroll
      for (int n = 0; n < 8; ++n)
        acc[m][n] = mfma16x16x32(af1[m], bf1[n], acc[m][n]);
    __builtin_amdgcn_s_setprio(0);

    asm volatile("s_waitcnt vmcnt(0)" ::: "memory");
    __builtin_amdgcn_sched_barrier(0);
    __builtin_amdgcn_s_barrier();
    __builtin_amdgcn_sched_barrier(0);
  }

  if (mode == 0) {
    #pragma unroll
    for (int m = 0; m < 4; ++m)
      #pragma unroll
      for (int n = 0; n < 8; ++n)
        #pragma unroll
        for (int j = 0; j < 4; ++j) {
          int row = bm + wr * 64 + m * 16 + g4 * 4 + j;
          int col = bn + wc * 128 + n * 16 + fr;
          Cf[(size_t)row * 2048 + col] = acc[m][n][j];
        }
    return;
  }

  // ---- fused QKV epilogue ----
  const int colbase = bn + wc * 128;          // wave-uniform, multiple of 128
  const int proj = colbase >> 11;             // 0=Q 1=K 2=V
  const int hh = (colbase & 2047) >> 7;
  if (proj == 2) {
    #pragma unroll
    for (int m = 0; m < 4; ++m) {
      int row0 = bm + wr * 64 + m * 16 + g4 * 4;
      int b_ = row0 >> 12, sr = row0 & 4095;
      #pragma unroll
      for (int n = 0; n < 8; ++n) {
        int d_ = n * 16 + fr;
        bf16x4 pkv;
        #pragma unroll
        for (int j = 0; j < 4; ++j) pkv[j] = (bf16_t)acc[m][n][j];
        *(bf16x4*)&outVT[(((size_t)(b_ * 16 + hh)) * 128 + d_) * 4096 + sr] = pkv;
      }
    }
  } else {
    bf16_t* dst_ = proj ? outK : outQ;
    #pragma unroll
    for (int m = 0; m < 4; ++m) {
      int row0 = bm + wr * 64 + m * 16 + g4 * 4;
      int b_ = row0 >> 12, s0 = row0 & 4095;
      size_t hbase = ((size_t)(b_ * 16 + hh)) * 4096;
      #pragma unroll
      for (int n = 0; n < 4; ++n) {
        int d = n * 16 + fr;
        #pragma unroll
        for (int j = 0; j < 4; ++j) {
          int s = s0 + j;
          float c  = cosT[s * 64 + d];
          float sn = sinT[s * 64 + d];
          float x0 = acc[m][n][j], x1 = acc[m][n + 4][j];
          dst_[(hbase + s) * 128 + d]      = (bf16_t)(x0 * c - x1 * sn);
          dst_[(hbase + s) * 128 + d + 64] = (bf16_t)(x1 * c + x0 * sn);
        }
      }
    }
  }
}

// ---------------- sparse flash attention (KVBLK=32, 4 blocks/CU) ------------
// block = (b,h,qt): 512 threads, 8 waves x 16 q-rows. LDS = 40KB exactly
// (K 2x8KB + V^T 2x8KB + P 8KB) -> 4 blocks/CU: cross-block cover for the
// per-step barrier. Active tiles only (tsel<=qt), packed 5-bit reg list;
// 4 steps of 32 toks per tile; stage s+1 before compute s; 1 barrier/step.
// Mask only local tile; defer-max (T13). Swapped QK^T / PV.
__global__ __launch_bounds__(512, 4) void attn_kernel(
    const bf16_t* __restrict__ Qf, const bf16_t* __restrict__ Kf,
    const bf16_t* __restrict__ Vt, const int* __restrict__ anchors,
    bf16_t* __restrict__ outB)   // [B,S,2048] bf16
{
  __shared__ bf16_t SH[20480];   // 40KB: K[2][4096] | V[2][4096] | P[8][512]
  bf16_t* Klb = SH;              // Kl[p] = SH + p*4096      ([32 tok][128 d])
  bf16_t* Vlb = SH + 8192;       // Vl[p] = Vlb + p*4096     ([128 d][32 tok])
  bf16_t* Pb  = SH + 16384;      // P(w)  = Pb + w*512       ([16 q][32 tok])
  const int orig = blockIdx.x;
  const int blk = (orig & 7) * 128 + (orig >> 3);   // XCD-chunked swizzle
  const int qt = 31 - (blk & 31);                   // long blocks first
  const int h = (blk >> 5) & 15, b = blk >> 9;
  const int bh = b * 16 + h;
  const int tid = threadIdx.x, w = tid >> 6, l = tid & 63;
  const int fr = l & 15, g4 = l >> 4;
  const float scale = 0.08838834764831845f;   // 1/sqrt(128)

  // ---- packed active-tile list (identical in every thread) ----
  const int* anc = anchors + ((size_t)bh * 32 + qt) * 7;
  unsigned long long pk = 0;
  int nt = 0;
  #pragma unroll
  for (int t = 0; t < 7; ++t) {
    int v = anc[t];
    if (v <= qt) { pk |= (unsigned long long)v << (5 * nt); ++nt; }
  }
  pk |= (unsigned long long)qt << (5 * nt); ++nt;   // local tile last
  const int NS = nt * 4;                            // 4 quarter-steps per tile

  const bf16_t* Qbase = Qf + (size_t)bh * 4096 * 128;
  const bf16_t* Kbase = Kf + (size_t)bh * 4096 * 128;
  const bf16_t* Vbase = Vt + (size_t)bh * 128 * 4096;
  char* P = (char*)(Pb + w * 512);

  // stage one 32-tok quarter: K [32][128] (16 chunks/row, ^(r&7)),
  // V^T [128][32] (4 chunks/row, ^(r&3)); 1 K-load + 1 V-load per thread.
  auto STAGE = [&](int tb2, int p) {
    const bf16_t* ksrc = Kbase + (size_t)tb2 * 128;
    const bf16_t* vsrc = Vbase + tb2;
    char* kd = (char*)(Klb + p * 4096);
    char* vd = (char*)(Vlb + p * 4096);
    int kr = tid >> 4, kcol = tid & 15;
    async_copy16(ksrc + (size_t)kr * 128 + (size_t)((kcol ^ (kr & 7)) * 8),
                 kd + tid * 16);
    int vr = tid >> 2, vcol = tid & 3;
    async_copy16(vsrc + (size_t)vr * 4096 + (size_t)((vcol ^ (vr & 3)) * 8),
                 vd + tid * 16);
  };

  // Q fragments (B-operand: col = q-row, k-chunk g4*8), direct from global
  const int qrow = qt * 128 + w * 16 + fr;
  bf16x8 aq[4];
  #pragma unroll
  for (int kc = 0; kc < 4; ++kc)
    aq[kc] = *(const bf16x8*)(Qbase + (size_t)qrow * 128 + kc * 32 + g4 * 8);

  STAGE((int)(pk & 31) * 128, 0);
  __syncthreads();   // step-0 buffers landed

  float mrun = -1e30f, lrun = 0.f;
  f32x4 o[8];
  #pragma unroll
  for (int nd = 0; nd < 8; ++nd) o[nd] = (f32x4){0.f, 0.f, 0.f, 0.f};

  for (int s = 0; s < NS; ++s) {
    const int p = s & 1;
    const int ts = (int)((pk >> (5 * (s >> 2))) & 31);
    const int qq = s & 3;                     // quarter within tile
    const bool domask = (ts == qt);
    if (s + 1 < NS) {
      int s1 = s + 1;
      int ts1 = (int)((pk >> (5 * (s1 >> 2))) & 31);
      STAGE(ts1 * 128 + (s1 & 3) * 32, p ^ 1);
    }

    // ---- S^T = K Q^T from Kl[p]: sc[n], rows=tok(g4*4+j), cols=q(fr) ----
    const char* Klp = (const char*)(Klb + p * 4096);
    f32x4 sc[2];
    sc[0] = (f32x4){0.f, 0.f, 0.f, 0.f};
    sc[1] = (f32x4){0.f, 0.f, 0.f, 0.f};
    #pragma unroll
    for (int kc = 0; kc < 4; ++kc) {
      bf16x8 kf[2];
      #pragma unroll
      for (int n = 0; n < 2; ++n) {
        int r = n * 16 + fr;
        kf[n] = *(const bf16x8*)(Klp + r * 256 + (((kc * 4 + g4) ^ (r & 7)) << 4));
      }
      sc[0] = mfma16x16x32(kf[0], aq[kc], sc[0]);
      sc[1] = mfma16x16x32(kf[1], aq[kc], sc[1]);
    }

    // ---- mask (local tile only) + online softmax over 8 values ----
    float rmax = -1e30f;
    if (domask) {
      const int qr = w * 16 + fr;            // row within tile
      #pragma unroll
      for (int n = 0; n < 2; ++n)
        #pragma unroll
        for (int j = 0; j < 4; ++j) {
          float lg = sc[n][j] * scale;
          int tok = qq * 32 + n * 16 + g4 * 4 + j;
          if (tok > qr) lg = -1e10f;
          sc[n][j] = lg;
          rmax = fmaxf(rmax, lg);
        }
    } else {
      #pragma unroll
      for (int n = 0; n < 2; ++n)
        #pragma unroll
        for (int j = 0; j < 4; ++j) {
          float lg = sc[n][j] * scale;
          sc[n][j] = lg;
          rmax = fmaxf(rmax, lg);
        }
    }
    rmax = fmaxf(rmax, __shfl_xor(rmax, 16));
    rmax = fmaxf(rmax, __shfl_xor(rmax, 32));
    if (__any(rmax > mrun + 8.f)) {          // defer-max (T13)
      float mnew = fmaxf(mrun, rmax);
      float alpha = __expf(mrun - mnew);
      lrun *= alpha;
      #pragma unroll
      for (int nd = 0; nd < 8; ++nd)
        #pragma unroll
        for (int j = 0; j < 4; ++j) o[nd][j] *= alpha;
      mrun = mnew;
    }
    float rsum = 0.f;
    #pragma unroll
    for (int n = 0; n < 2; ++n) {
      bf16x4 pkv;
      #pragma unroll
      for (int j = 0; j < 4; ++j) {
        float pe = __expf(sc[n][j] - mrun);
        rsum += pe;
        pkv[j] = (bf16_t)pe;
      }
      // P [16 q][32 tok]: 64B rows of 4 chunks, chunk = n*2+(g4>>1), ^(fr&3)
      int off = fr * 64 + ((((n << 1) | (g4 >> 1)) ^ (fr & 3)) << 4) + ((g4 & 1) << 3);
      *(bf16x4*)(P + off) = pkv;
    }
    rsum += __shfl_xor(rsum, 16);
    rsum += __shfl_xor(rsum, 32);
    lrun += rsum;

    // ---- O^T += V^T P from Vl[p] + per-wave P (single K=32 chunk) ----
    {
      const char* Vlp = (const char*)(Vlb + p * 4096);
      bf16x8 av[8];
      #pragma unroll
      for (int nd = 0; nd < 8; ++nd) {
        int r = nd * 16 + fr;
        av[nd] = *(const bf16x8*)(Vlp + r * 64 + ((g4 ^ (r & 3)) << 4));
      }
      bf16x8 bp = *(const bf16x8*)(P + fr * 64 + ((g4 ^ (fr & 3)) << 4));
      #pragma unroll
      for (int nd = 0; nd < 8; ++nd)
        o[nd] = mfma16x16x32(av[nd], bp, o[nd]);
    }
    __syncthreads();   // next staging landed + all waves done with buf p
  }

  // ---- epilogue: normalize; O^T -> per-wave scratch (K/V region dead) ----
  {
    char* E = (char*)SH + w * 4096;          // 16 rows x 256B per wave (32KB)
    float inv = 1.0f / lrun;
    #pragma unroll
    for (int nd = 0; nd < 8; ++nd) {
      bf16x4 pkv;
      #pragma unroll
      for (int j = 0; j < 4; ++j) pkv[j] = (bf16_t)(o[nd][j] * inv);
      int off = fr * 256 + ((((nd << 1) | (g4 >> 1)) ^ (fr & 7)) << 4) + ((g4 & 1) << 3);
      *(bf16x4*)(E + off) = pkv;
    }
    #pragma unroll
    for (int i = 0; i < 4; ++i) {
      int r = i * 4 + g4;
      int off = r * 256 + ((fr ^ (r & 7)) << 4);
      bf16x8 vrow = *(const bf16x8*)(E + off);
      size_t gaddr = (((size_t)b * 4096 + qt * 128 + w * 16 + r) * 2048)
                     + h * 128 + fr * 8;
      *(bf16x8*)(outB + gaddr) = vrow;
    }
  }
}

// ---------------------------------------------------------------------------
// workspace layout (bytes)
#define OFF_XB   ((size_t)0)            // x bf16            [8192][2048]  32MB
#define OFF_WCAT ((size_t)33554432)     // concat wq^T|wk^T|wv^T bf16 [6144][2048] 24MB
#define OFF_WOT  ((size_t)58720256)     // wo^T bf16 [2048][2048] 8MB
#define OFF_QF   ((size_t)67108864)     // Q bf16 [B,H,S,D]  32MB
#define OFF_KF   ((size_t)100663296)    // K bf16 [B,H,S,D]  32MB
#define OFF_AT   ((size_t)134217728)    // attn out [B,S,2048] bf16 32MB
#define OFF_VT   ((size_t)167772160)    // V^T bf16 [B,H,D,S] 32MB

extern "C" void kernel_launch(void* const* d_in, const int* in_sizes, int n_in,
                              void* d_out, int out_size, void* d_ws, size_t ws_size,
                              hipStream_t stream) {
  (void)in_sizes; (void)n_in; (void)out_size; (void)ws_size;
  const float* x    = (const float*)d_in[0];
  const float* wq   = (const float*)d_in[1];
  const float* wk   = (const float*)d_in[2];
  const float* wv   = (const float*)d_in[3];
  const float* wo   = (const float*)d_in[4];
  const float* cosT = (const float*)d_in[5];
  const float* sinT = (const float*)d_in[6];
  const int*   anc  = (const int*)d_in[7];
  float* out = (float*)d_out;
  char* ws = (char*)d_ws;

  bf16_t* xb   = (bf16_t*)(ws + OFF_XB);
  bf16_t* wcat = (bf16_t*)(ws + OFF_WCAT);
  bf16_t* wot  = (bf16_t*)(ws + OFF_WOT);
  bf16_t* Qf   = (bf16_t*)(ws + OFF_QF);
  bf16_t* Kf   = (bf16_t*)(ws + OFF_KF);
  bf16_t* Vt   = (bf16_t*)(ws + OFF_VT);
  bf16_t* attnB = (bf16_t*)(ws + OFF_AT);

  cvt_f32_bf16<<<16384, 256, 0, stream>>>(x, xb);
  wtrans4<<<dim3(32, 32, 4), 256, 0, stream>>>(wq, wk, wv, wo, wcat, wot);
  // fused QKV projection + RoPE + V^T (grid 768 = 32 M-blocks x 24 N-blocks)
  gemm256<<<768, 512, 0, stream>>>(xb, wcat, 24, 1, nullptr, Qf, Kf, Vt, cosT, sinT);
  attn_kernel<<<1024, 512, 0, stream>>>(Qf, Kf, Vt, anc, attnB);
  // output projection (grid 256 = 32 x 8)
  gemm256<<<256, 512, 0, stream>>>(attnB, wot, 8, 0, out, nullptr, nullptr, nullptr,
                                   nullptr, nullptr);
}

// Round 12
// 355.839 us; speedup vs baseline: 1.1954x; 1.0556x over previous
//
#include <hip/hip_runtime.h>
#include <hip/hip_bf16.h>

// ---------------------------------------------------------------------------
// KascadeReuseAttention: B=2,S=4096,H=16,D=128, TILE=128, T=32, TOPK=7(+local)
// R12: consolidation. GEMM = R9 loop (best measured) + chunk-local M-fastest
// block mapping (B-panel L2 locality; isolated change). attn reverted to R9's
// KVBLK=64 512-thread version (best measured). wtrans4 merged kept.
// ---------------------------------------------------------------------------

typedef __bf16 bf16_t;
using bf16x8 = __attribute__((ext_vector_type(8))) __bf16;
using bf16x4 = __attribute__((ext_vector_type(4))) __bf16;
using f32x4  = __attribute__((ext_vector_type(4))) float;

typedef const __attribute__((address_space(1))) void* gas_ptr;
typedef __attribute__((address_space(3))) void* las_ptr;

__device__ __forceinline__ void async_copy16(const void* g, void* l) {
  __builtin_amdgcn_global_load_lds((gas_ptr)g, (las_ptr)l, 16, 0, 0);
}

__device__ __forceinline__ f32x4 mfma16x16x32(bf16x8 a, bf16x8 b, f32x4 c) {
  return __builtin_amdgcn_mfma_f32_16x16x32_bf16(a, b, c, 0, 0, 0);
}

// ---------------- elementwise f32 -> bf16 (vectorized) ----------------------
__global__ void cvt_f32_bf16(const float* __restrict__ X, bf16_t* __restrict__ Y) {
  int idx = blockIdx.x * 256 + threadIdx.x;
  float4 v = ((const float4*)X)[idx];
  bf16x4 r;
  r.x = (bf16_t)v.x; r.y = (bf16_t)v.y; r.z = (bf16_t)v.z; r.w = (bf16_t)v.w;
  ((bf16x4*)Y)[idx] = r;
}

// -------- weight transpose+convert x4 in one launch: W f32 -> Wt bf16 -------
__global__ void wtrans4(const float* __restrict__ wq, const float* __restrict__ wk,
                        const float* __restrict__ wv, const float* __restrict__ wo,
                        bf16_t* __restrict__ wcat, bf16_t* __restrict__ wot) {
  __shared__ bf16_t t[64][66];
  const int z = blockIdx.z;
  const float* W = (z == 0) ? wq : (z == 1) ? wk : (z == 2) ? wv : wo;
  bf16_t* Wt = (z == 3) ? wot : (wcat + (size_t)z * 2048 * 2048);
  const int r0 = blockIdx.x * 64, c0 = blockIdx.y * 64;
  const int tx = threadIdx.x & 63, ty = threadIdx.x >> 6;
  #pragma unroll
  for (int i = 0; i < 16; ++i) {
    int r = ty + 4 * i;
    t[r][tx] = (bf16_t)W[(size_t)(r0 + r) * 2048 + c0 + tx];
  }
  __syncthreads();
  #pragma unroll
  for (int i = 0; i < 16; ++i) {
    int n = ty + 4 * i;
    Wt[(size_t)(c0 + n) * 2048 + r0 + tx] = t[tx][n];
  }
}

// ---------------- GEMM 256x256 pipelined (R9 loop, M-fastest chunks) --------
// 8 waves as 4M x 2N (per-wave 64Mx128N; full head span in-thread for rope).
// LDS: 2-slot double buffer of A[256][64]+B[256][64] bf16 panels (128KiB).
// Swizzle: rows are 8 x 16B chunks; LDS[row][ch] = global[row][ch^(row&7)].
// Phase phi (32, BK=64): {kc0 frags | STAGE(phi+1) | kc0 MFMA x32 | kc1 frags
// | kc1 MFMA x32 | vmcnt(0) | raw s_barrier}.
// Block map: XCD chunk = cpx consecutive swz; within chunk M varies fastest
// (RM=cpx/nb rows) -> instantaneous B working set ~12MB vs 26MB (L2 locality).
// mode 0: f32 C row-major [8192][2048] (nb=8).
// mode 1: fused QKV (nb=24): Q,K rope'd bf16 [B,H,S,D]; V -> V^T [B,H,D,S].
__global__ __launch_bounds__(512, 2) void gemm256(
    const bf16_t* __restrict__ A, const bf16_t* __restrict__ Bt,
    int nb, int mode, float* __restrict__ Cf,
    bf16_t* __restrict__ outQ, bf16_t* __restrict__ outK,
    bf16_t* __restrict__ outVT,
    const float* __restrict__ cosT, const float* __restrict__ sinT)
{
  __shared__ bf16_t Apan[2][16384];   // [256 rows][64 k] bf16 = 32KB per slot
  __shared__ bf16_t Bpan[2][16384];
  const int bid = blockIdx.x;
  const int cpx = gridDim.x >> 3;
  const int swz = (bid & 7) * cpx + (bid >> 3);   // XCD-chunked (grid%8==0)
  const int RM = cpx / nb;                        // M-rows per chunk (=4 here)
  const int bm = ((swz / cpx) * RM + (swz % RM)) * 256;   // M fastest in chunk
  const int bn = ((swz % cpx) / RM) * 256;
  const int tid = threadIdx.x;
  const int w = tid >> 6, l = tid & 63;
  const int wr = w >> 1, wc = w & 1;              // 4M x 2N
  const int fr = l & 15, g4 = l >> 4;

  const bf16_t* aS[4];
  const bf16_t* bS[4];
  int dst[4];
  #pragma unroll
  for (int i = 0; i < 4; ++i) {
    int c = tid + i * 512;
    int row = c >> 3, ch = c & 7;
    int sc = (ch ^ (row & 7)) * 8;
    aS[i] = A  + (size_t)(bm + row) * 2048 + sc;
    bS[i] = Bt + (size_t)(bn + row) * 2048 + sc;
    dst[i] = c * 16;
  }

  int aOff[2][4], bOff[2][8];
  #pragma unroll
  for (int kc = 0; kc < 2; ++kc) {
    #pragma unroll
    for (int m = 0; m < 4; ++m) {
      int R = wr * 64 + m * 16 + fr;
      aOff[kc][m] = R * 128 + (((kc * 4 + g4) ^ (R & 7)) << 4);
    }
    #pragma unroll
    for (int n = 0; n < 8; ++n) {
      int R = wc * 128 + n * 16 + fr;
      bOff[kc][n] = R * 128 + (((kc * 4 + g4) ^ (R & 7)) << 4);
    }
  }

  f32x4 acc[4][8];
  #pragma unroll
  for (int m = 0; m < 4; ++m)
    #pragma unroll
    for (int n = 0; n < 8; ++n) acc[m][n] = (f32x4){0.f, 0.f, 0.f, 0.f};

  auto STAGE = [&](int t) {        // stage K-tile t (64 wide) into slot t&1
    const int slot = t & 1;
    const int kb = t * 64;
    char* dA = (char*)&Apan[slot][0];
    char* dB = (char*)&Bpan[slot][0];
    #pragma unroll
    for (int i = 0; i < 4; ++i) {
      async_copy16(aS[i] + kb, dA + dst[i]);
      async_copy16(bS[i] + kb, dB + dst[i]);
    }
  };

  STAGE(0);
  __syncthreads();   // prologue: tile 0 landed (full drain, once)

  #pragma unroll 1
  for (int phi = 0; phi < 32; ++phi) {
    const int slot = phi & 1;
    const char* pa = (const char*)&Apan[slot][0];
    const char* pb = (const char*)&Bpan[slot][0];

    bf16x8 af0[4], bf0[8];
    #pragma unroll
    for (int m = 0; m < 4; ++m) af0[m] = *(const bf16x8*)(pa + aOff[0][m]);
    #pragma unroll
    for (int n = 0; n < 8; ++n) bf0[n] = *(const bf16x8*)(pb + bOff[0][n]);
    if (phi < 31) STAGE(phi + 1);
    __builtin_amdgcn_s_setprio(1);
    #pragma unroll
    for (int m = 0; m < 4; ++m)
      #pragma unroll
      for (int n = 0; n < 8; ++n)
        acc[m][n] = mfma16x16x32(af0[m], bf0[n], acc[m][n]);
    __builtin_amdgcn_s_setprio(0);

    bf16x8 af1[4], bf1[8];
    #pragma unroll
    for (int m = 0; m < 4; ++m) af1[m] = *(const bf16x8*)(pa + aOff[1][m]);
    #pragma unroll
    for (int n = 0; n < 8; ++n) bf1[n] = *(const bf16x8*)(pb + bOff[1][n]);
    __builtin_amdgcn_s_setprio(1);
    #pragma unroll
    for (int m = 0; m < 4; ++m)
      #pragma unroll
      for (int n = 0; n < 8; ++n)
        acc[m][n] = mfma16x16x32(af1[m], bf1[n], acc[m][n]);
    __builtin_amdgcn_s_setprio(0);

    asm volatile("s_waitcnt vmcnt(0)" ::: "memory");
    __builtin_amdgcn_sched_barrier(0);
    __builtin_amdgcn_s_barrier();
    __builtin_amdgcn_sched_barrier(0);
  }

  if (mode == 0) {
    #pragma unroll
    for (int m = 0; m < 4; ++m)
      #pragma unroll
      for (int n = 0; n < 8; ++n)
        #pragma unroll
        for (int j = 0; j < 4; ++j) {
          int row = bm + wr * 64 + m * 16 + g4 * 4 + j;
          int col = bn + wc * 128 + n * 16 + fr;
          Cf[(size_t)row * 2048 + col] = acc[m][n][j];
        }
    return;
  }

  // ---- fused QKV epilogue ----
  const int colbase = bn + wc * 128;          // wave-uniform, multiple of 128
  const int proj = colbase >> 11;             // 0=Q 1=K 2=V
  const int hh = (colbase & 2047) >> 7;
  if (proj == 2) {
    #pragma unroll
    for (int m = 0; m < 4; ++m) {
      int row0 = bm + wr * 64 + m * 16 + g4 * 4;
      int b_ = row0 >> 12, sr = row0 & 4095;
      #pragma unroll
      for (int n = 0; n < 8; ++n) {
        int d_ = n * 16 + fr;
        bf16x4 pkv;
        #pragma unroll
        for (int j = 0; j < 4; ++j) pkv[j] = (bf16_t)acc[m][n][j];
        *(bf16x4*)&outVT[(((size_t)(b_ * 16 + hh)) * 128 + d_) * 4096 + sr] = pkv;
      }
    }
  } else {
    bf16_t* dst_ = proj ? outK : outQ;
    #pragma unroll
    for (int m = 0; m < 4; ++m) {
      int row0 = bm + wr * 64 + m * 16 + g4 * 4;
      int b_ = row0 >> 12, s0 = row0 & 4095;
      size_t hbase = ((size_t)(b_ * 16 + hh)) * 4096;
      #pragma unroll
      for (int n = 0; n < 4; ++n) {
        int d = n * 16 + fr;
        #pragma unroll
        for (int j = 0; j < 4; ++j) {
          int s = s0 + j;
          float c  = cosT[s * 64 + d];
          float sn = sinT[s * 64 + d];
          float x0 = acc[m][n][j], x1 = acc[m][n + 4][j];
          dst_[(hbase + s) * 128 + d]      = (bf16_t)(x0 * c - x1 * sn);
          dst_[(hbase + s) * 128 + d + 64] = (bf16_t)(x1 * c + x0 * sn);
        }
      }
    }
  }
}

// ---------------- sparse flash attention (R9 version: KVBLK=64) -------------
// block = (b,h,qt): 512 threads, 8 waves x 16 q-rows, LDS exactly 80KB ->
// 2 blocks/CU. Active tiles only (tsel<=qt), packed 5-bit reg list. KVBLK=64
// double-buffered via gload_lds (source-preswizzled chunk^=row&7); stage s+1
// before compute s; 1 barrier/step. Mask only local tile; defer-max (T13).
// Swapped QK^T / PV; P packed bf16x4 per-wave LDS.
__global__ __launch_bounds__(512, 4) void attn_kernel(
    const bf16_t* __restrict__ Qf, const bf16_t* __restrict__ Kf,
    const bf16_t* __restrict__ Vt, const int* __restrict__ anchors,
    bf16_t* __restrict__ outB)   // [B,S,2048] bf16
{
  __shared__ bf16_t Kl[2][8192];    // [64 tok][128 d] swizzled, 16KB each
  __shared__ bf16_t Vl[2][8192];    // [128 d][64 tok] swizzled, 16KB each
  __shared__ bf16_t Pbuf[8][1024];  // per-wave 2KB  (total LDS = 80KB exact)
  const int orig = blockIdx.x;
  const int blk = (orig & 7) * 128 + (orig >> 3);   // XCD-chunked swizzle
  const int qt = 31 - (blk & 31);                   // long blocks first
  const int h = (blk >> 5) & 15, b = blk >> 9;
  const int bh = b * 16 + h;
  const int tid = threadIdx.x, w = tid >> 6, l = tid & 63;
  const int fr = l & 15, g4 = l >> 4;
  const float scale = 0.08838834764831845f;   // 1/sqrt(128)

  // ---- packed active-tile list (identical in every thread) ----
  const int* anc = anchors + ((size_t)bh * 32 + qt) * 7;
  unsigned long long pk = 0;
  int nt = 0;
  #pragma unroll
  for (int t = 0; t < 7; ++t) {
    int v = anc[t];
    if (v <= qt) { pk |= (unsigned long long)v << (5 * nt); ++nt; }
  }
  pk |= (unsigned long long)qt << (5 * nt); ++nt;   // local tile last
  const int NS = nt * 2;

  const bf16_t* Qbase = Qf + (size_t)bh * 4096 * 128;
  const bf16_t* Kbase = Kf + (size_t)bh * 4096 * 128;
  const bf16_t* Vbase = Vt + (size_t)bh * 128 * 4096;
  char* P = (char*)&Pbuf[w][0];

  auto STAGE = [&](int tb2, int p) {
    const bf16_t* ksrc = Kbase + (size_t)tb2 * 128;
    const bf16_t* vsrc = Vbase + tb2;
    char* kd = (char*)&Kl[p][0];
    char* vd = (char*)&Vl[p][0];
    #pragma unroll
    for (int i = 0; i < 2; ++i) {
      int c = tid + i * 512;                 // 0..1023
      int kr = c >> 4, kcol = c & 15;        // K: 64 rows x 16 chunks
      async_copy16(ksrc + (size_t)kr * 128 + (size_t)((kcol ^ (kr & 7)) * 8),
                   kd + c * 16);
      int vr = c >> 3, vcol = c & 7;         // V^T: 128 rows x 8 chunks
      async_copy16(vsrc + (size_t)vr * 4096 + (size_t)((vcol ^ (vr & 7)) * 8),
                   vd + c * 16);
    }
  };

  // Q fragments (B-operand: col = q-row, k-chunk g4*8), direct from global
  const int qrow = qt * 128 + w * 16 + fr;
  bf16x8 aq[4];
  #pragma unroll
  for (int kc = 0; kc < 4; ++kc)
    aq[kc] = *(const bf16x8*)(Qbase + (size_t)qrow * 128 + kc * 32 + g4 * 8);

  STAGE((int)(pk & 31) * 128, 0);
  __syncthreads();   // step-0 buffers landed

  float mrun = -1e30f, lrun = 0.f;
  f32x4 o[8];
  #pragma unroll
  for (int nd = 0; nd < 8; ++nd) o[nd] = (f32x4){0.f, 0.f, 0.f, 0.f};

  for (int s = 0; s < NS; ++s) {
    const int p = s & 1;
    const int ts = (int)((pk >> (5 * (s >> 1))) & 31);
    const bool domask = (ts == qt);
    if (s + 1 < NS) {
      int s1 = s + 1;
      int ts1 = (int)((pk >> (5 * (s1 >> 1))) & 31);
      STAGE(ts1 * 128 + (s1 & 1) * 64, p ^ 1);
    }

    // ---- S^T = K Q^T from Kl[p]: sc[n], rows=tok(g4*4+j), cols=q(fr) ----
    f32x4 sc[4];
    #pragma unroll
    for (int n = 0; n < 4; ++n) sc[n] = (f32x4){0.f, 0.f, 0.f, 0.f};
    #pragma unroll
    for (int kc = 0; kc < 4; ++kc) {
      bf16x8 kf[4];
      #pragma unroll
      for (int n = 0; n < 4; ++n) {
        int r = n * 16 + fr;
        kf[n] = *(const bf16x8*)((const char*)&Kl[p][0] +
                 r * 256 + (((kc * 4 + g4) ^ (r & 7)) << 4));
      }
      #pragma unroll
      for (int n = 0; n < 4; ++n)
        sc[n] = mfma16x16x32(kf[n], aq[kc], sc[n]);
    }

    // ---- mask (local tile only) + online softmax ----
    float rmax = -1e30f;
    if (domask) {
      const int qr = w * 16 + fr;            // row within tile
      #pragma unroll
      for (int n = 0; n < 4; ++n)
        #pragma unroll
        for (int j = 0; j < 4; ++j) {
          float lg = sc[n][j] * scale;
          int tok = (s & 1) * 64 + n * 16 + g4 * 4 + j;
          if (tok > qr) lg = -1e10f;
          sc[n][j] = lg;
          rmax = fmaxf(rmax, lg);
        }
    } else {
      #pragma unroll
      for (int n = 0; n < 4; ++n)
        #pragma unroll
        for (int j = 0; j < 4; ++j) {
          float lg = sc[n][j] * scale;
          sc[n][j] = lg;
          rmax = fmaxf(rmax, lg);
        }
    }
    rmax = fmaxf(rmax, __shfl_xor(rmax, 16));
    rmax = fmaxf(rmax, __shfl_xor(rmax, 32));
    if (__any(rmax > mrun + 8.f)) {          // defer-max (T13)
      float mnew = fmaxf(mrun, rmax);
      float alpha = __expf(mrun - mnew);
      lrun *= alpha;
      #pragma unroll
      for (int nd = 0; nd < 8; ++nd)
        #pragma unroll
        for (int j = 0; j < 4; ++j) o[nd][j] *= alpha;
      mrun = mnew;
    }
    float rsum = 0.f;
    #pragma unroll
    for (int n = 0; n < 4; ++n) {
      bf16x4 pkv;
      #pragma unroll
      for (int j = 0; j < 4; ++j) {
        float pe = __expf(sc[n][j] - mrun);
        rsum += pe;
        pkv[j] = (bf16_t)pe;
      }
      int off = fr * 128 + ((((n << 1) | (g4 >> 1)) ^ (fr & 7)) << 4) + ((g4 & 1) << 3);
      *(bf16x4*)(P + off) = pkv;
    }
    rsum += __shfl_xor(rsum, 16);
    rsum += __shfl_xor(rsum, 32);
    lrun += rsum;

    // ---- O^T += V^T P from Vl[p] + per-wave P ----
    #pragma unroll
    for (int kc2 = 0; kc2 < 2; ++kc2) {
      bf16x8 av[8];
      #pragma unroll
      for (int nd = 0; nd < 8; ++nd) {
        int r = nd * 16 + fr;
        av[nd] = *(const bf16x8*)((const char*)&Vl[p][0] +
                  r * 128 + (((kc2 * 4 + g4) ^ (r & 7)) << 4));
      }
      bf16x8 bp = *(const bf16x8*)(P + fr * 128 + ((((kc2 << 2) | g4) ^ (fr & 7)) << 4));
      #pragma unroll
      for (int nd = 0; nd < 8; ++nd)
        o[nd] = mfma16x16x32(av[nd], bp, o[nd]);
    }
    __syncthreads();   // next staging landed + all waves done with buf p
  }

  // ---- epilogue: normalize; O^T -> per-wave scratch (Kl dead) -> store ----
  {
    char* E = (char*)&Kl[0][0] + w * 4096;   // 16 rows x 256B per wave
    float inv = 1.0f / lrun;
    #pragma unroll
    for (int nd = 0; nd < 8; ++nd) {
      bf16x4 pkv;
      #pragma unroll
      for (int j = 0; j < 4; ++j) pkv[j] = (bf16_t)(o[nd][j] * inv);
      int off = fr * 256 + ((((nd << 1) | (g4 >> 1)) ^ (fr & 7)) << 4) + ((g4 & 1) << 3);
      *(bf16x4*)(E + off) = pkv;
    }
    #pragma unroll
    for (int i = 0; i < 4; ++i) {
      int r = i * 4 + g4;
      int off = r * 256 + ((fr ^ (r & 7)) << 4);
      bf16x8 vrow = *(const bf16x8*)(E + off);
      size_t gaddr = (((size_t)b * 4096 + qt * 128 + w * 16 + r) * 2048)
                     + h * 128 + fr * 8;
      *(bf16x8*)(outB + gaddr) = vrow;
    }
  }
}

// ---------------------------------------------------------------------------
// workspace layout (bytes)
#define OFF_XB   ((size_t)0)            // x bf16            [8192][2048]  32MB
#define OFF_WCAT ((size_t)33554432)     // concat wq^T|wk^T|wv^T bf16 [6144][2048] 24MB
#define OFF_WOT  ((size_t)58720256)     // wo^T bf16 [2048][2048] 8MB
#define OFF_QF   ((size_t)67108864)     // Q bf16 [B,H,S,D]  32MB
#define OFF_KF   ((size_t)100663296)    // K bf16 [B,H,S,D]  32MB
#define OFF_AT   ((size_t)134217728)    // attn out [B,S,2048] bf16 32MB
#define OFF_VT   ((size_t)167772160)    // V^T bf16 [B,H,D,S] 32MB

extern "C" void kernel_launch(void* const* d_in, const int* in_sizes, int n_in,
                              void* d_out, int out_size, void* d_ws, size_t ws_size,
                              hipStream_t stream) {
  (void)in_sizes; (void)n_in; (void)out_size; (void)ws_size;
  const float* x    = (const float*)d_in[0];
  const float* wq   = (const float*)d_in[1];
  const float* wk   = (const float*)d_in[2];
  const float* wv   = (const float*)d_in[3];
  const float* wo   = (const float*)d_in[4];
  const float* cosT = (const float*)d_in[5];
  const float* sinT = (const float*)d_in[6];
  const int*   anc  = (const int*)d_in[7];
  float* out = (float*)d_out;
  char* ws = (char*)d_ws;

  bf16_t* xb   = (bf16_t*)(ws + OFF_XB);
  bf16_t* wcat = (bf16_t*)(ws + OFF_WCAT);
  bf16_t* wot  = (bf16_t*)(ws + OFF_WOT);
  bf16_t* Qf   = (bf16_t*)(ws + OFF_QF);
  bf16_t* Kf   = (bf16_t*)(ws + OFF_KF);
  bf16_t* Vt   = (bf16_t*)(ws + OFF_VT);
  bf16_t* attnB = (bf16_t*)(ws + OFF_AT);

  cvt_f32_bf16<<<16384, 256, 0, stream>>>(x, xb);
  wtrans4<<<dim3(32, 32, 4), 256, 0, stream>>>(wq, wk, wv, wo, wcat, wot);
  // fused QKV projection + RoPE + V^T (grid 768 = 32 M-blocks x 24 N-blocks)
  gemm256<<<768, 512, 0, stream>>>(xb, wcat, 24, 1, nullptr, Qf, Kf, Vt, cosT, sinT);
  attn_kernel<<<1024, 512, 0, stream>>>(Qf, Kf, Vt, anc, attnB);
  // output projection (grid 256 = 32 x 8)
  gemm256<<<256, 512, 0, stream>>>(attnB, wot, 8, 0, out, nullptr, nullptr, nullptr,
                                   nullptr, nullptr);
}